// Round 13
// baseline (112.042 us; speedup 1.0000x reference)
//
#include <hip/hip_runtime.h>
#include <hip/hip_fp16.h>

#define B_  8
#define C_  256
#define H_  64
#define W_  64
#define G_  4
#define CG_ 64
#define HW_ 4096

#define WROWS 10
#define WCOLS 24
#define KPAD  256                // 8 K-steps of 32 (240 real + 16 zero-pad)
#define SROW  260                // fp32 row stride; 260%32==4 -> ~2-way banks

typedef _Float16 f16x8 __attribute__((ext_vector_type(8)));
typedef float    f32x4 __attribute__((ext_vector_type(4)));

// ---------------------------------------------------------------------------
// K1: NCHW fp32 -> fragment-major fp16  Xt[b][g][y][x/8][ch][x%8]
// ---------------------------------------------------------------------------
__global__ __launch_bounds__(256) void to_tiled_f16(const float* __restrict__ in,
                                                    _Float16* __restrict__ out) {
  __shared__ unsigned int tile[64][33];
  const int y = blockIdx.x, g = blockIdx.y, b = blockIdx.z;
  const int tid = threadIdx.x;
  const float* src = in + ((size_t)(b * C_) + g * CG_) * HW_ + y * W_;
  _Float16* dst = out + (size_t)((b * G_ + g) * H_ + y) * (8 * 64 * 8);

  const int ch = tid >> 2;
  const int xh = (tid & 3) * 8;
  const float* sp = src + (size_t)ch * HW_ + xh * 2;
#pragma unroll
  for (int i = 0; i < 4; ++i) {
    const float4 v = *(const float4*)(sp + i * 4);
    const unsigned u0 = ((unsigned)__half_as_ushort(__float2half(v.y)) << 16) |
                        __half_as_ushort(__float2half(v.x));
    const unsigned u1 = ((unsigned)__half_as_ushort(__float2half(v.w)) << 16) |
                        __half_as_ushort(__float2half(v.z));
    tile[ch][xh + i * 2]     = u0;
    tile[ch][xh + i * 2 + 1] = u1;
  }
  __syncthreads();
#pragma unroll
  for (int rr = 0; rr < 2; ++rr) {
    const int r  = tid + rr * 256;
    const int xc = r >> 6, c2 = r & 63;
    uint4 o;
    o.x = tile[c2][xc * 4 + 0];
    o.y = tile[c2][xc * 4 + 1];
    o.z = tile[c2][xc * 4 + 2];
    o.w = tile[c2][xc * 4 + 3];
    *(uint4*)(dst + (size_t)r * 8) = o;
  }
}

// ---------------------------------------------------------------------------
// K2: deformable sampling as MFMA with fire-and-forget S-build.
//   out[64ch x 64px] = X[64ch x K] * S[K x 64px], K = 10x24 window (pad 256).
//   - S fp32 in LDS, built via atomicAdd -> ds_add_f32 (no return, no chain).
//     One builder lane per px row; same-lane LDS ops are ordered -> replay-
//     deterministic. Zero-weight corners skipped (no aliasing redirect).
//   - B-fragment: 2x ds_read_b128 fp32 + cvt to f16x8 (mapping k = ry*24+rx,
//     identical convention to the r10-12 validated kernel).
//   - A-fragment: Xt chunks; chunk = 4*step+q; row=chunk/3 col=(chunk%3)*8;
//     chunks 30,31 are pad (B=0) with row clamped in-bounds.
//   - escapes (corner outside 10x24, ~11/block) -> exact epilogue recompute.
//   - LDS 68.1 KB (gfx950 allows >64KB static) -> 2 blocks/CU.
// ---------------------------------------------------------------------------
struct SM {
  float S[64][SROW];      // 66560 B
  int   escN[64];         // 256 B
  short escK[64][10];     // 1280 B
};                        // 68096 B

__global__ __launch_bounds__(256, 2) void deform_mfma(const float* __restrict__ x,
                                                      const _Float16* __restrict__ xt,
                                                      const float* __restrict__ off,
                                                      const float* __restrict__ msk,
                                                      float* __restrict__ out) {
  __shared__ SM sm;

  const int orig = blockIdx.x;                    // 0..2047; 2048 % 8 == 0
  const int wgid = (orig & 7) * 256 + (orig >> 3);
  const int tile = wgid & 63;
  const int bg   = wgid >> 6;
  const int ho0  = (tile >> 2) * 4;
  const int wo0  = (tile & 3) * 16;
  const int b    = bg >> 2;
  const int g    = bg & 3;
  const int tid  = threadIdx.x;

  const int wy0 = min(max(ho0 - 3, 0), H_ - WROWS);  // rows [wy0, +10)
  const int wx0 = min(max(wo0 - 8, 0), W_ - WCOLS);  // cols [wx0, +24), %8==0
  const float* slab = x + (size_t)(b * C_ + g * CG_) * HW_;

  // ---- zero S (incl. K-pad region) ----
  {
    float4* z = (float4*)sm.S;
    for (int i = tid; i < 64 * SROW / 4; i += 256)
      z[i] = make_float4(0.f, 0.f, 0.f, 0.f);
  }
  __syncthreads();

  // ---- S-build: one builder per px, spread over all 4 waves ----
  if ((tid & 3) == 0) {
    const int px = tid >> 2;
    const int ho = ho0 + (px >> 4);
    const int wo = wo0 + (px & 15);
    const int pixoff = ho * W_ + wo;

    float dyv[9], dxv[9], mv[9];
#pragma unroll
    for (int k = 0; k < 9; ++k) {
      const size_t obo = (size_t)(b * 72 + (g * 9 + k) * 2) * HW_ + pixoff;
      dyv[k] = off[obo];
      dxv[k] = off[obo + HW_];
      mv[k]  = msk[(size_t)(b * 36 + g * 9 + k) * HW_ + pixoff];
    }

    int en = 0;
#pragma unroll
    for (int k = 0; k < 9; ++k) {
      const int ky = k / 3, kx = k - ky * 3;
      const float py = (float)(ho - 1 + ky) + dyv[k];
      const float qx = (float)(wo - 1 + kx) + dxv[k];
      const float fy = floorf(py), fx = floorf(qx);
      const int y0 = (int)fy, x0 = (int)fx;
      const int y1 = y0 + 1,  x1 = x0 + 1;
      const float ly = py - fy, lx = qx - fx;
      const float m = mv[k];

      const bool vy0 = (unsigned)y0 < (unsigned)H_, vy1 = (unsigned)y1 < (unsigned)H_;
      const bool vx0 = (unsigned)x0 < (unsigned)W_, vx1 = (unsigned)x1 < (unsigned)W_;
      const float w00 = (vy0 && vx0) ? (1.f - ly) * (1.f - lx) * m : 0.f;
      const float w01 = (vy0 && vx1) ? (1.f - ly) * lx * m         : 0.f;
      const float w10 = (vy1 && vx0) ? ly * (1.f - lx) * m         : 0.f;
      const float w11 = (vy1 && vx1) ? ly * lx * m                 : 0.f;

      const int ry0 = y0 - wy0, ry1 = y1 - wy0;
      const int rx0 = x0 - wx0, rx1 = x1 - wx0;
      const bool iy0 = (unsigned)ry0 < WROWS, iy1 = (unsigned)ry1 < WROWS;
      const bool ix0 = (unsigned)rx0 < WCOLS, ix1 = (unsigned)rx1 < WCOLS;
      const bool ok = (w00 == 0.f || (iy0 && ix0)) && (w01 == 0.f || (iy0 && ix1)) &&
                      (w10 == 0.f || (iy1 && ix0)) && (w11 == 0.f || (iy1 && ix1));

      if (ok) {  // ds_add_f32: no return, no dependency chain
        if (w00 != 0.f) atomicAdd(&sm.S[px][ry0 * WCOLS + rx0], w00);
        if (w01 != 0.f) atomicAdd(&sm.S[px][ry0 * WCOLS + rx1], w01);
        if (w10 != 0.f) atomicAdd(&sm.S[px][ry1 * WCOLS + rx0], w10);
        if (w11 != 0.f) atomicAdd(&sm.S[px][ry1 * WCOLS + rx1], w11);
      } else {
        if (en < 10) sm.escK[px][en] = (short)k;
        ++en;
      }
    }
    sm.escN[px] = min(en, 10);
  }
  __syncthreads();

  // ---- MFMA: wave wv owns px-tile wv; loops 4 ch-bands; 8 K-steps ----
  const int wv   = tid >> 6;
  const int lane = tid & 63;
  const int arow = lane & 15;
  const int q    = lane >> 4;
  const int prow = wv * 16 + arow;

  f32x4 acc[4];
#pragma unroll
  for (int mb = 0; mb < 4; ++mb) acc[mb] = (f32x4){0.f, 0.f, 0.f, 0.f};

  const size_t bgh = (size_t)(b * G_ + g) * H_;

#pragma unroll
  for (int i = 0; i < 8; ++i) {
    // B: 8 fp32 from S row, cvt to f16x8
    const float4 s0 = *(const float4*)&sm.S[prow][i * 32 + q * 8];
    const float4 s1 = *(const float4*)&sm.S[prow][i * 32 + q * 8 + 4];
    f16x8 bf;
    bf[0] = (_Float16)s0.x; bf[1] = (_Float16)s0.y;
    bf[2] = (_Float16)s0.z; bf[3] = (_Float16)s0.w;
    bf[4] = (_Float16)s1.x; bf[5] = (_Float16)s1.y;
    bf[6] = (_Float16)s1.z; bf[7] = (_Float16)s1.w;

    // A: chunk = 4i+q -> window (row, col); chunks 30,31 are pad (B==0)
    int chunk = 4 * i + q;
    int wr = chunk / 3, wc = chunk - wr * 3;
    if (chunk >= 30) { wr = WROWS - 1; wc = 0; }
    const int y = wy0 + wr;
    const int xchunk = (wx0 >> 3) + wc;
    const _Float16* xp = xt + (((bgh + y) * 8 + xchunk) * 64) * 8 + arow * 8;
    const f16x8 a0 = *(const f16x8*)(xp);
    const f16x8 a1 = *(const f16x8*)(xp + 16 * 8);
    const f16x8 a2 = *(const f16x8*)(xp + 32 * 8);
    const f16x8 a3 = *(const f16x8*)(xp + 48 * 8);

    acc[0] = __builtin_amdgcn_mfma_f32_16x16x32_f16(a0, bf, acc[0], 0, 0, 0);
    acc[1] = __builtin_amdgcn_mfma_f32_16x16x32_f16(a1, bf, acc[1], 0, 0, 0);
    acc[2] = __builtin_amdgcn_mfma_f32_16x16x32_f16(a2, bf, acc[2], 0, 0, 0);
    acc[3] = __builtin_amdgcn_mfma_f32_16x16x32_f16(a3, bf, acc[3], 0, 0, 0);
  }

  // ---- epilogue: exact recompute of escaped taps + coalesced stores ----
  float* ob = out + (size_t)(b * C_ + g * CG_) * HW_;
  const int colx = arow;
  const int rgrp = q * 4;
  const int px_  = wv * 16 + colx;
  const int ho   = ho0 + wv;
  const int wo   = wo0 + colx;
  const int gofs = ho * W_ + wo;
  const int en   = sm.escN[px_];

#pragma unroll
  for (int mb = 0; mb < 4; ++mb) {
    float c0 = 0.f, c1 = 0.f, c2 = 0.f, c3 = 0.f;
    if (en > 0) {
      for (int j = 0; j < en; ++j) {
        const int k  = (int)sm.escK[px_][j];
        const int ky = k / 3, kx = k - ky * 3;
        const size_t obo = (size_t)(b * 72 + (g * 9 + k) * 2) * HW_ + gofs;
        const float dy = off[obo];
        const float dx = off[obo + HW_];
        const float m  = msk[(size_t)(b * 36 + g * 9 + k) * HW_ + gofs];

        const float py = (float)(ho - 1 + ky) + dy;
        const float qx = (float)(wo - 1 + kx) + dx;
        const float fy = floorf(py), fx = floorf(qx);
        const int y0 = (int)fy, x0 = (int)fx;
        const int y1 = y0 + 1,  x1 = x0 + 1;
        const float ly = py - fy, lx = qx - fx;

        const bool vy0 = (unsigned)y0 < (unsigned)H_, vy1 = (unsigned)y1 < (unsigned)H_;
        const bool vx0 = (unsigned)x0 < (unsigned)W_, vx1 = (unsigned)x1 < (unsigned)W_;
        const float w00 = (vy0 && vx0) ? (1.f - ly) * (1.f - lx) * m : 0.f;
        const float w01 = (vy0 && vx1) ? (1.f - ly) * lx * m         : 0.f;
        const float w10 = (vy1 && vx0) ? ly * (1.f - lx) * m         : 0.f;
        const float w11 = (vy1 && vx1) ? ly * lx * m                 : 0.f;

        const int y0c = min(max(y0, 0), H_ - 1), y1c = min(max(y1, 0), H_ - 1);
        const int x0c = min(max(x0, 0), W_ - 1), x1c = min(max(x1, 0), W_ - 1);
        const int o00 = y0c * W_ + x0c, o01 = y0c * W_ + x1c;
        const int o10 = y1c * W_ + x0c, o11 = y1c * W_ + x1c;

        const float* p0 = slab + (size_t)(mb * 16 + rgrp) * HW_;
        c0 += w00 * p0[o00] + w01 * p0[o01] + w10 * p0[o10] + w11 * p0[o11];
        const float* p1 = p0 + HW_;
        c1 += w00 * p1[o00] + w01 * p1[o01] + w10 * p1[o10] + w11 * p1[o11];
        const float* p2 = p0 + 2 * HW_;
        c2 += w00 * p2[o00] + w01 * p2[o01] + w10 * p2[o10] + w11 * p2[o11];
        const float* p3 = p0 + 3 * HW_;
        c3 += w00 * p3[o00] + w01 * p3[o01] + w10 * p3[o10] + w11 * p3[o11];
      }
    }
    const int chb = mb * 16 + rgrp;
    ob[(size_t)(chb + 0) * HW_ + gofs] = acc[mb][0] + c0;
    ob[(size_t)(chb + 1) * HW_ + gofs] = acc[mb][1] + c1;
    ob[(size_t)(chb + 2) * HW_ + gofs] = acc[mb][2] + c2;
    ob[(size_t)(chb + 3) * HW_ + gofs] = acc[mb][3] + c3;
  }
}

// ---------------------------------------------------------------------------
// Fallback (no workspace): fp32 NCHW gathers, 4 ch/thread.
// ---------------------------------------------------------------------------
__global__ __launch_bounds__(256) void deform_f32_nchw(const float* __restrict__ x,
                                                       const float* __restrict__ off,
                                                       const float* __restrict__ msk,
                                                       float* __restrict__ out) {
  __shared__ int4   s_o[144];
  __shared__ float4 s_w[144];
  const int woq = blockIdx.x;
  const int ho  = blockIdx.y;
  const int b   = blockIdx.z >> 2;
  const int g   = blockIdx.z & 3;
  const int tid = threadIdx.x;

  if (tid < 144) {
    const int wi = tid / 9, k = tid - wi * 9;
    const int wo = woq * 16 + wi;
    const int ky = k / 3, kx = k - ky * 3;
    const size_t ob = (size_t)(b * 72 + (g * 9 + k) * 2) * HW_ + ho * W_ + wo;
    const float dy = off[ob];
    const float dx = off[ob + HW_];
    const float m  = msk[(size_t)(b * 36 + g * 9 + k) * HW_ + ho * W_ + wo];
    const float py = (float)(ho - 1 + ky) + dy;
    const float px = (float)(wo - 1 + kx) + dx;
    const float fy = floorf(py), fx = floorf(px);
    const int y0 = (int)fy, x0 = (int)fx;
    const int y1 = y0 + 1,  x1 = x0 + 1;
    const float ly = py - fy, lx = px - fx;
    const bool vy0 = (unsigned)y0 < (unsigned)H_, vy1 = (unsigned)y1 < (unsigned)H_;
    const bool vx0 = (unsigned)x0 < (unsigned)W_, vx1 = (unsigned)x1 < (unsigned)W_;
    const float wy0 = (1.f - ly) * m, wy1 = ly * m;
    float4 w;
    w.x = (vy0 && vx0) ? wy0 * (1.f - lx) : 0.f;
    w.y = (vy0 && vx1) ? wy0 * lx         : 0.f;
    w.z = (vy1 && vx0) ? wy1 * (1.f - lx) : 0.f;
    w.w = (vy1 && vx1) ? wy1 * lx         : 0.f;
    const int y0c = min(max(y0, 0), H_ - 1), y1c = min(max(y1, 0), H_ - 1);
    const int x0c = min(max(x0, 0), W_ - 1), x1c = min(max(x1, 0), W_ - 1);
    s_o[tid] = make_int4(y0c * W_ + x0c, y0c * W_ + x1c, y1c * W_ + x0c, y1c * W_ + x1c);
    s_w[tid] = w;
  }
  __syncthreads();

  const int ci = tid & 15, wi = tid >> 4;
  const float* xb = x + (size_t)(b * C_ + g * CG_ + ci * 4) * HW_;
  float a0 = 0.f, a1 = 0.f, a2 = 0.f, a3 = 0.f;
#pragma unroll
  for (int k = 0; k < 9; ++k) {
    const int e = wi * 9 + k;
    const int4   o = s_o[e];
    const float4 w = s_w[e];
    a0 += w.x * xb[o.x] + w.y * xb[o.y] + w.z * xb[o.z] + w.w * xb[o.w];
    const float* x1p = xb + HW_;
    a1 += w.x * x1p[o.x] + w.y * x1p[o.y] + w.z * x1p[o.z] + w.w * x1p[o.w];
    const float* x2p = xb + 2 * HW_;
    a2 += w.x * x2p[o.x] + w.y * x2p[o.y] + w.z * x2p[o.z] + w.w * x2p[o.w];
    const float* x3p = xb + 3 * HW_;
    a3 += w.x * x3p[o.x] + w.y * x3p[o.y] + w.z * x3p[o.z] + w.w * x3p[o.w];
  }
  float* ob = out + (size_t)(b * C_ + g * CG_ + ci * 4) * HW_ + ho * W_ + woq * 16 + wi;
  ob[0] = a0; ob[HW_] = a1; ob[2 * HW_] = a2; ob[3 * HW_] = a3;
}

// ---------------------------------------------------------------------------
extern "C" void kernel_launch(void* const* d_in, const int* in_sizes, int n_in,
                              void* d_out, int out_size, void* d_ws, size_t ws_size,
                              hipStream_t stream) {
  const float* inp = (const float*)d_in[0];
  const float* off = (const float*)d_in[1];
  const float* msk = (const float*)d_in[2];
  float* out = (float*)d_out;

  const size_t need = (size_t)B_ * C_ * HW_ * sizeof(_Float16);  // 16.8 MB
  if (ws_size >= need) {
    _Float16* xt = (_Float16*)d_ws;
    to_tiled_f16<<<dim3(H_, G_, B_), 256, 0, stream>>>(inp, xt);
    deform_mfma<<<dim3(2048), 256, 0, stream>>>(inp, xt, off, msk, out);
  } else {
    deform_f32_nchw<<<dim3(4, H_, B_ * G_), 256, 0, stream>>>(inp, off, msk, out);
  }
}

// Round 14
// 47.425 us; speedup vs baseline: 2.3625x; 2.3625x over previous
//
#include <hip/hip_runtime.h>
#include <hip/hip_fp16.h>

#define B_  8
#define C_  256
#define H_  64
#define W_  64
#define G_  4
#define CG_ 64
#define K_  9
#define HW_ (H_ * W_)  // 4096

// ---------------------------------------------------------------------------
// Kernel 1: NCHW fp32 -> group-major NHWC fp16  [B,C,HW] -> [B,G,HW,CG]
// (r2-proven; ~8 us, coalesced both sides)
// ---------------------------------------------------------------------------
__global__ __launch_bounds__(256) void to_ghwc_f16(const float* __restrict__ in,
                                                   __half* __restrict__ out) {
  __shared__ unsigned int tile[32][65];  // [channel-pair][pixel]
  const int b  = blockIdx.z;
  const int p0 = blockIdx.x * 64;
  const int g  = blockIdx.y;
  const int tid = threadIdx.x;
  const float* src = in + (size_t)b * C_ * HW_ + (size_t)g * CG_ * HW_;
  __half* dst = out + ((size_t)(b * G_ + g) * HW_) * CG_;

  const int px  = tid & 63;
  const int cp0 = tid >> 6;
#pragma unroll
  for (int i = 0; i < 8; ++i) {
    const int cp = cp0 + i * 4;
    const int c  = cp * 2;
    const float v0 = src[(size_t)c * HW_ + p0 + px];
    const float v1 = src[(size_t)(c + 1) * HW_ + p0 + px];
    const unsigned int lo = (unsigned int)__half_as_ushort(__float2half(v0));
    const unsigned int hi = (unsigned int)__half_as_ushort(__float2half(v1));
    tile[cp][px] = lo | (hi << 16);
  }
  __syncthreads();

  const int cpair = tid & 31;
  const int pr0   = tid >> 5;
#pragma unroll
  for (int i = 0; i < 8; ++i) {
    const int p = pr0 + i * 8;
    *(unsigned int*)(dst + (size_t)(p0 + p) * CG_ + 2 * cpair) = tile[cpair][p];
  }
}

// ---------------------------------------------------------------------------
// Kernel 2: deformable sampling from [B,G,HW,CG] fp16 (r6 dataflow,
// occupancy-first repack):
//   - block = 128 threads (2 waves), tile = one output row slice 1x32 px.
//     LDS 9.2 KB -> 16 blocks/CU (HW workgroup cap) = 32 waves/CU, 2.5x r6.
//   - phase 1: 288 (px,tap) params -> LDS (coalesced 128B off/mask reads).
//   - phase 2: 2 px x 8 ch per thread; 8 independent 16B saddr gathers per
//     tap; fp32 accumulate; DIRECT stores (32B segments per ch per wave),
//     no staging phase, single barrier per block.
//   - XCD swizzle: 4096 blocks % 8 == 0; bg-major chunks per XCD keep the
//     2MB group slab L2-resident (r6-verified: FETCH ~= compulsory).
// ---------------------------------------------------------------------------
__global__ __launch_bounds__(128, 8) void deform_row(const __half* __restrict__ x,
                                                     const float* __restrict__ off,
                                                     const float* __restrict__ msk,
                                                     float* __restrict__ out) {
  __shared__ int4   s_o[288];
  __shared__ float4 s_w[288];

  const int orig = blockIdx.x;                    // 0..4095
  const int wgid = (orig & 7) * 512 + (orig >> 3);
  const int bg   = wgid >> 7;                     // 0..31 (b*4+g), bg-major/XCD
  const int loc  = wgid & 127;
  const int ho   = loc >> 1;                      // 0..63
  const int wo0  = (loc & 1) * 32;                // 0 or 32
  const int b    = bg >> 2;
  const int g    = bg & 3;
  const int tid  = threadIdx.x;

  // ---- phase 1: params for 32 px x 9 taps ----
  for (int e = tid; e < 288; e += 128) {
    const int sl = e & 31;            // slot == px offset within row slice
    const int k  = e >> 5;
    const int wo = wo0 + sl;
    const int ky = k / 3, kx = k - ky * 3;
    const size_t ob = (size_t)(b * 72 + (g * 9 + k) * 2) * HW_ + ho * W_ + wo;
    const float dy = off[ob];
    const float dx = off[ob + HW_];
    const float m  = msk[(size_t)(b * 36 + g * 9 + k) * HW_ + ho * W_ + wo];

    const float py  = (float)(ho - 1 + ky) + dy;
    const float pxx = (float)(wo - 1 + kx) + dx;
    const float fy = floorf(py), fx = floorf(pxx);
    const int y0 = (int)fy, x0 = (int)fx;
    const int y1 = y0 + 1,  x1 = x0 + 1;
    const float ly = py - fy, lx = pxx - fx;

    const bool vy0 = ((unsigned)y0 < (unsigned)H_), vy1 = ((unsigned)y1 < (unsigned)H_);
    const bool vx0 = ((unsigned)x0 < (unsigned)W_), vx1 = ((unsigned)x1 < (unsigned)W_);
    const float wy0 = (1.f - ly) * m, wy1 = ly * m;

    float4 w;
    w.x = (vy0 && vx0) ? wy0 * (1.f - lx) : 0.f;
    w.y = (vy0 && vx1) ? wy0 * lx         : 0.f;
    w.z = (vy1 && vx0) ? wy1 * (1.f - lx) : 0.f;
    w.w = (vy1 && vx1) ? wy1 * lx         : 0.f;

    const int y0c = min(max(y0, 0), H_ - 1), y1c = min(max(y1, 0), H_ - 1);
    const int x0c = min(max(x0, 0), W_ - 1), x1c = min(max(x1, 0), W_ - 1);

    int4 o;  // BYTE offsets into group slab (pix * CG * 2 = pix << 7)
    o.x = (y0c * W_ + x0c) << 7;
    o.y = (y0c * W_ + x1c) << 7;
    o.z = (y1c * W_ + x0c) << 7;
    o.w = (y1c * W_ + x1c) << 7;
    s_o[e] = o;
    s_w[e] = w;
  }
  __syncthreads();

  // ---- phase 2: 2 px x 8 ch per thread, global saddr gathers ----
  const int ci16 = (tid & 7) * 16;   // byte offset of channel octet
  const int wi   = tid >> 3;         // slot 0..15; pixels wi and wi+16
  const char* base = (const char*)x + (size_t)(b * G_ + g) * (HW_ * CG_ * 2);

  float a0[8] = {0.f, 0.f, 0.f, 0.f, 0.f, 0.f, 0.f, 0.f};
  float a1[8] = {0.f, 0.f, 0.f, 0.f, 0.f, 0.f, 0.f, 0.f};

#pragma unroll
  for (int k = 0; k < 9; ++k) {
    const int4   oA = s_o[k * 32 + wi];
    const float4 wA = s_w[k * 32 + wi];
    const int4   oB = s_o[k * 32 + wi + 16];
    const float4 wB = s_w[k * 32 + wi + 16];

    const float4 rA0 = *(const float4*)(base + (oA.x + ci16));
    const float4 rA1 = *(const float4*)(base + (oA.y + ci16));
    const float4 rA2 = *(const float4*)(base + (oA.z + ci16));
    const float4 rA3 = *(const float4*)(base + (oA.w + ci16));
    const float4 rB0 = *(const float4*)(base + (oB.x + ci16));
    const float4 rB1 = *(const float4*)(base + (oB.y + ci16));
    const float4 rB2 = *(const float4*)(base + (oB.z + ci16));
    const float4 rB3 = *(const float4*)(base + (oB.w + ci16));

    const __half* hA0 = (const __half*)&rA0;
    const __half* hA1 = (const __half*)&rA1;
    const __half* hA2 = (const __half*)&rA2;
    const __half* hA3 = (const __half*)&rA3;
    const __half* hB0 = (const __half*)&rB0;
    const __half* hB1 = (const __half*)&rB1;
    const __half* hB2 = (const __half*)&rB2;
    const __half* hB3 = (const __half*)&rB3;
#pragma unroll
    for (int j = 0; j < 8; ++j) {
      float s0 = a0[j];
      s0 = fmaf(wA.x, __half2float(hA0[j]), s0);
      s0 = fmaf(wA.y, __half2float(hA1[j]), s0);
      s0 = fmaf(wA.z, __half2float(hA2[j]), s0);
      s0 = fmaf(wA.w, __half2float(hA3[j]), s0);
      a0[j] = s0;
      float s1 = a1[j];
      s1 = fmaf(wB.x, __half2float(hB0[j]), s1);
      s1 = fmaf(wB.y, __half2float(hB1[j]), s1);
      s1 = fmaf(wB.z, __half2float(hB2[j]), s1);
      s1 = fmaf(wB.w, __half2float(hB3[j]), s1);
      a1[j] = s1;
    }
  }

  // ---- direct stores: per ch per wave = 8 contiguous dwords x 2 ----
  float* ob = out + (size_t)(b * C_ + g * CG_) * HW_ + ho * W_ + wo0;
#pragma unroll
  for (int j = 0; j < 8; ++j) {
    const int ch = (tid & 7) * 8 + j;
    ob[(size_t)ch * HW_ + wi]      = a0[j];
    ob[(size_t)ch * HW_ + wi + 16] = a1[j];
  }
}

// ---------------------------------------------------------------------------
// Fallback (no workspace): fp32 NCHW gathers, 4 ch/thread (replay-clean).
// ---------------------------------------------------------------------------
__global__ __launch_bounds__(256) void deform_f32_nchw(const float* __restrict__ x,
                                                       const float* __restrict__ off,
                                                       const float* __restrict__ msk,
                                                       float* __restrict__ out) {
  __shared__ int4   s_o[144];
  __shared__ float4 s_w[144];
  const int woq = blockIdx.x;
  const int ho  = blockIdx.y;
  const int b   = blockIdx.z >> 2;
  const int g   = blockIdx.z & 3;
  const int tid = threadIdx.x;

  if (tid < 144) {
    const int wi = tid / 9, k = tid - wi * 9;
    const int wo = woq * 16 + wi;
    const int ky = k / 3, kx = k - ky * 3;
    const size_t ob = (size_t)(b * 72 + (g * 9 + k) * 2) * HW_ + ho * W_ + wo;
    const float dy = off[ob];
    const float dx = off[ob + HW_];
    const float m  = msk[(size_t)(b * 36 + g * 9 + k) * HW_ + ho * W_ + wo];
    const float py = (float)(ho - 1 + ky) + dy;
    const float px = (float)(wo - 1 + kx) + dx;
    const float fy = floorf(py), fx = floorf(px);
    const int y0 = (int)fy, x0 = (int)fx;
    const int y1 = y0 + 1,  x1 = x0 + 1;
    const float ly = py - fy, lx = px - fx;
    const bool vy0 = ((unsigned)y0 < (unsigned)H_), vy1 = ((unsigned)y1 < (unsigned)H_);
    const bool vx0 = ((unsigned)x0 < (unsigned)W_), vx1 = ((unsigned)x1 < (unsigned)W_);
    const float wy0 = (1.f - ly) * m, wy1 = ly * m;
    float4 w;
    w.x = (vy0 && vx0) ? wy0 * (1.f - lx) : 0.f;
    w.y = (vy0 && vx1) ? wy0 * lx         : 0.f;
    w.z = (vy1 && vx0) ? wy1 * (1.f - lx) : 0.f;
    w.w = (vy1 && vx1) ? wy1 * lx         : 0.f;
    const int y0c = min(max(y0, 0), H_ - 1), y1c = min(max(y1, 0), H_ - 1);
    const int x0c = min(max(x0, 0), W_ - 1), x1c = min(max(x1, 0), W_ - 1);
    s_o[tid] = make_int4(y0c * W_ + x0c, y0c * W_ + x1c, y1c * W_ + x0c, y1c * W_ + x1c);
    s_w[tid] = w;
  }
  __syncthreads();

  const int ci = tid & 15, wi = tid >> 4;
  const float* xb = x + (size_t)(b * C_ + g * CG_ + ci * 4) * HW_;
  float a0 = 0.f, a1 = 0.f, a2 = 0.f, a3 = 0.f;
#pragma unroll
  for (int k = 0; k < 9; ++k) {
    const int e = wi * 9 + k;
    const int4   o = s_o[e];
    const float4 w = s_w[e];
    a0 += w.x * xb[o.x] + w.y * xb[o.y] + w.z * xb[o.z] + w.w * xb[o.w];
    const float* x1p = xb + HW_;
    a1 += w.x * x1p[o.x] + w.y * x1p[o.y] + w.z * x1p[o.z] + w.w * x1p[o.w];
    const float* x2p = xb + 2 * HW_;
    a2 += w.x * x2p[o.x] + w.y * x2p[o.y] + w.z * x2p[o.z] + w.w * x2p[o.w];
    const float* x3p = xb + 3 * HW_;
    a3 += w.x * x3p[o.x] + w.y * x3p[o.y] + w.z * x3p[o.z] + w.w * x3p[o.w];
  }
  float* ob = out + (size_t)(b * C_ + g * CG_ + ci * 4) * HW_ + ho * W_ + woq * 16 + wi;
  ob[0] = a0; ob[HW_] = a1; ob[2 * HW_] = a2; ob[3 * HW_] = a3;
}

// ---------------------------------------------------------------------------
extern "C" void kernel_launch(void* const* d_in, const int* in_sizes, int n_in,
                              void* d_out, int out_size, void* d_ws, size_t ws_size,
                              hipStream_t stream) {
  const float* inp = (const float*)d_in[0];
  const float* off = (const float*)d_in[1];
  const float* msk = (const float*)d_in[2];
  float* out = (float*)d_out;

  const size_t need = (size_t)B_ * C_ * HW_ * sizeof(__half);  // 16.8 MB
  if (ws_size >= need) {
    __half* xt = (__half*)d_ws;
    to_ghwc_f16<<<dim3(HW_ / 64, G_, B_), 256, 0, stream>>>(inp, xt);
    deform_row<<<dim3(4096), 128, 0, stream>>>(xt, off, msk, out);
  } else {
    deform_f32_nchw<<<dim3(4, H_, B_ * G_), 256, 0, stream>>>(inp, off, msk, out);
  }
}